// Round 16
// baseline (706.011 us; speedup 1.0000x reference)
//
#include <hip/hip_runtime.h>
#include <stdint.h>
#include <math.h>

// ---------------- types ----------------
typedef __attribute__((ext_vector_type(4))) float f32x4;
typedef __attribute__((ext_vector_type(8))) short s16x8;   // 8 x bf16 (4 VGPRs)
typedef __attribute__((ext_vector_type(4))) unsigned short u16x4;

__device__ __forceinline__ unsigned short f2b(float x) {
    union { float f; uint32_t u; } v; v.f = x;
    uint32_t r = v.u + 0x7FFFu + ((v.u >> 16) & 1u);   // round-to-nearest-even
    return (unsigned short)(r >> 16);
}
__device__ __forceinline__ float b2f(unsigned short u) {
    union { uint32_t u; float f; } v; v.u = (uint32_t)u << 16;
    return v.f;
}

__device__ __forceinline__ void gload16(const unsigned short* g, unsigned short* l) {
    __builtin_amdgcn_global_load_lds(
        (const __attribute__((address_space(1))) unsigned int*)(const void*)g,
        (__attribute__((address_space(3))) unsigned int*)(void*)l,
        16, 0, 0);
}

// tanh-form GELU (max abs dev from exact erf-GELU ~3e-4; budget 0.123)
__device__ __forceinline__ float gelu_t(float u) {
    float z = 0.7978845608f * (u + 0.044715f * u * u * u);
    float ez = __expf(2.0f * z);
    float th = 1.0f - 2.0f / (ez + 1.0f);
    return 0.5f * u * (1.0f + th);
}

// ---------------- fused cast(4 weights) + LN1 in one launch ----------------
__global__ __launch_bounds__(256) void castln_kernel(
        const float* __restrict__ x, const float* __restrict__ lw,
        const float* __restrict__ lb, unsigned short* __restrict__ lout,
        const float* __restrict__ a, int na, const float* __restrict__ b, int nb,
        const float* __restrict__ c, int nc, const float* __restrict__ d, int nd,
        unsigned short* __restrict__ oa, unsigned short* __restrict__ ob,
        unsigned short* __restrict__ oc, unsigned short* __restrict__ od) {
    const int tid = threadIdx.x;
    if (blockIdx.x < 4096) {
        const long row = blockIdx.x;
        f32x4 v = *(const f32x4*)(x + row * 1024 + tid * 4);
        float s  = v[0] + v[1] + v[2] + v[3];
        float sq = v[0]*v[0] + v[1]*v[1] + v[2]*v[2] + v[3]*v[3];
        #pragma unroll
        for (int off = 32; off; off >>= 1) {
            s  += __shfl_xor(s, off);
            sq += __shfl_xor(sq, off);
        }
        __shared__ float red[8];
        if ((tid & 63) == 0) { red[tid >> 6] = s; red[4 + (tid >> 6)] = sq; }
        __syncthreads();
        s  = red[0] + red[1] + red[2] + red[3];
        sq = red[4] + red[5] + red[6] + red[7];
        float mu  = s * (1.0f / 1024.0f);
        float var = sq * (1.0f / 1024.0f) - mu * mu;
        float rs  = rsqrtf(var + 1e-5f);
        f32x4 wv = *(const f32x4*)(lw + tid * 4);
        f32x4 bv = *(const f32x4*)(lb + tid * 4);
        u16x4 o;
        #pragma unroll
        for (int j = 0; j < 4; ++j) o[j] = f2b((v[j] - mu) * rs * wv[j] + bv[j]);
        *(u16x4*)(lout + row * 1024 + tid * 4) = o;
    } else {
        int i = (blockIdx.x - 4096) * 256 + tid;
        const float* src; unsigned short* dst; int off;
        if (i < na)                { src = a; dst = oa; off = i; }
        else if (i < na+nb)        { src = b; dst = ob; off = i - na; }
        else if (i < na+nb+nc)     { src = c; dst = oc; off = i - na - nb; }
        else if (i < na+nb+nc+nd)  { src = d; dst = od; off = i - na - nb - nc; }
        else return;
        f32x4 v = ((const f32x4*)src)[off];
        u16x4 o;
        #pragma unroll
        for (int j = 0; j < 4; ++j) o[j] = f2b(v[j]);
        ((u16x4*)dst)[off] = o;
    }
}

// ---------------- LayerNorm (standalone, LN2) ----------------
__global__ __launch_bounds__(256) void ln_kernel(const float* __restrict__ x,
                                                 const float* __restrict__ w,
                                                 const float* __restrict__ b,
                                                 unsigned short* __restrict__ out) {
    const long row = blockIdx.x;
    const int tid = threadIdx.x;
    f32x4 v = *(const f32x4*)(x + row * 1024 + tid * 4);
    float s  = v[0] + v[1] + v[2] + v[3];
    float sq = v[0]*v[0] + v[1]*v[1] + v[2]*v[2] + v[3]*v[3];
    #pragma unroll
    for (int off = 32; off; off >>= 1) {
        s  += __shfl_xor(s, off);
        sq += __shfl_xor(sq, off);
    }
    __shared__ float red[8];
    if ((tid & 63) == 0) { red[tid >> 6] = s; red[4 + (tid >> 6)] = sq; }
    __syncthreads();
    s  = red[0] + red[1] + red[2] + red[3];
    sq = red[4] + red[5] + red[6] + red[7];
    float mu  = s * (1.0f / 1024.0f);
    float var = sq * (1.0f / 1024.0f) - mu * mu;
    float rs  = rsqrtf(var + 1e-5f);
    f32x4 wv = *(const f32x4*)(w + tid * 4);
    f32x4 bv = *(const f32x4*)(b + tid * 4);
    u16x4 o;
    #pragma unroll
    for (int j = 0; j < 4; ++j) o[j] = f2b((v[j] - mu) * rs * wv[j] + bv[j]);
    *(u16x4*)(out + row * 1024 + tid * 4) = o;
}

// ---------------- fused attention pass 2 (R14-proven + NT att stores) ----------------
__global__ __launch_bounds__(256)
void attn2(const unsigned short* __restrict__ Qg,   // [64][1024][64] bf16, pre-scaled
           const unsigned short* __restrict__ Kg,   // [64][1024][64] bf16
           const unsigned short* __restrict__ Vt,   // [64][64][1024] bf16 (d-major)
           const float* __restrict__ mask,          // [1024][1024] f32
           const float* __restrict__ psum,          // [64][1024][16] partials
           float* __restrict__ att,                 // [64][1024][1024] fp32 out
           unsigned short* __restrict__ y) {        // [4096][1024] bf16 scatter
    __shared__ unsigned short Ks[2][64][72];
    __shared__ unsigned short Vs[2][64][72];
    __shared__ unsigned short Ps[4][16][72];
    __shared__ float invl_s[64];
    const int tid = threadIdx.x, lane = tid & 63, wid = tid >> 6;
    const int fr = lane & 15, fs = lane >> 4;
    const int bh = blockIdx.y, q0 = blockIdx.x * 64;

    if (tid < 64) {
        const float* p = psum + ((((long)bh << 10) + q0 + tid) << 4);
        f32x4 pa = *(const f32x4*)p,       pb = *(const f32x4*)(p + 4);
        f32x4 pc = *(const f32x4*)(p + 8), pd = *(const f32x4*)(p + 12);
        float s = (pa[0]+pa[1]+pa[2]+pa[3]) + (pb[0]+pb[1]+pb[2]+pb[3])
                + (pc[0]+pc[1]+pc[2]+pc[3]) + (pd[0]+pd[1]+pd[2]+pd[3]);
        invl_s[tid] = 1.0f / s;
    }

    const unsigned short* qp = Qg + ((long)bh << 16) + (long)(q0 + wid * 16 + fr) * 64 + fs * 8;
    const s16x8 aq0 = *(const s16x8*)qp;
    const s16x8 aq1 = *(const s16x8*)(qp + 32);

    const int srow = tid >> 2, scol = (tid & 3) * 16;
    const unsigned short* kbase = Kg + ((long)bh << 16) + (long)srow * 64 + scol;
    const unsigned short* vbase = Vt + ((long)bh << 16) + (long)srow * 1024 + scol;

    s16x8 k0a, k0b, v0a, v0b, k1a, k1b, v1a, v1b;
    k0a = *(const s16x8*)kbase;            k0b = *(const s16x8*)(kbase + 8);
    v0a = *(const s16x8*)vbase;            v0b = *(const s16x8*)(vbase + 8);
    k1a = *(const s16x8*)(kbase + 4096);   k1b = *(const s16x8*)(kbase + 4104);
    v1a = *(const s16x8*)(vbase + 64);     v1b = *(const s16x8*)(vbase + 72);

    f32x4 acc[4] = {};

#define AITER(KT, BUF, KA, KB, VA, VB)                                              \
    {                                                                               \
        *(s16x8*)&Ks[BUF][srow][scol]     = KA;                                     \
        *(s16x8*)&Ks[BUF][srow][scol + 8] = KB;                                     \
        *(s16x8*)&Vs[BUF][srow][scol]     = VA;                                     \
        *(s16x8*)&Vs[BUF][srow][scol + 8] = VB;                                     \
        __syncthreads();                                                            \
        if ((KT) + 2 < 16) {                                                        \
            const unsigned short* kp = kbase + (long)((KT) + 2) * 4096;             \
            const unsigned short* vp = vbase + ((KT) + 2) * 64;                     \
            KA = *(const s16x8*)kp;  KB = *(const s16x8*)(kp + 8);                  \
            VA = *(const s16x8*)vp;  VB = *(const s16x8*)(vp + 8);                  \
        }                                                                           \
        f32x4 s4[4];                                                                \
        _Pragma("unroll")                                                           \
        for (int n = 0; n < 4; ++n) {                                               \
            s16x8 b0 = *(const s16x8*)&Ks[BUF][n * 16 + fr][fs * 8];                \
            s16x8 b1 = *(const s16x8*)&Ks[BUF][n * 16 + fr][32 + fs * 8];           \
            f32x4 z = {};                                                           \
            z = __builtin_amdgcn_mfma_f32_16x16x32_bf16(aq0, b0, z, 0, 0, 0);       \
            z = __builtin_amdgcn_mfma_f32_16x16x32_bf16(aq1, b1, z, 0, 0, 0);       \
            s4[n] = z;                                                              \
        }                                                                           \
        _Pragma("unroll")                                                           \
        for (int r = 0; r < 4; ++r) {                                               \
            const long mb = ((long)(q0 + wid * 16 + fs * 4 + r) << 10) + (KT) * 64; \
            _Pragma("unroll")                                                       \
            for (int n = 0; n < 4; ++n) {                                           \
                float e = __expf(s4[n][r] + mask[mb + n * 16 + fr]);                \
                Ps[wid][fs * 4 + r][n * 16 + fr] = f2b(e);                          \
            }                                                                       \
        }                                                                           \
        {                                                                           \
            const float il = invl_s[srow];                                          \
            s16x8 p0 = *(const s16x8*)&Ps[wid][srow & 15][scol];                    \
            s16x8 p1 = *(const s16x8*)&Ps[wid][srow & 15][scol + 8];                \
            float* ap = att + ((long)bh << 20) + ((long)(q0 + srow) << 10)          \
                        + (KT) * 64 + scol;                                         \
            f32x4 o;                                                                \
            _Pragma("unroll") for (int j = 0; j < 4; ++j) o[j] = b2f((unsigned short)p0[j]) * il; \
            __builtin_nontemporal_store(o, (f32x4*)ap);                             \
            _Pragma("unroll") for (int j = 0; j < 4; ++j) o[j] = b2f((unsigned short)p0[4 + j]) * il; \
            __builtin_nontemporal_store(o, (f32x4*)(ap + 4));                       \
            _Pragma("unroll") for (int j = 0; j < 4; ++j) o[j] = b2f((unsigned short)p1[j]) * il; \
            __builtin_nontemporal_store(o, (f32x4*)(ap + 8));                       \
            _Pragma("unroll") for (int j = 0; j < 4; ++j) o[j] = b2f((unsigned short)p1[4 + j]) * il; \
            __builtin_nontemporal_store(o, (f32x4*)(ap + 12));                      \
        }                                                                           \
        {                                                                           \
            s16x8 pa0 = *(const s16x8*)&Ps[wid][fr][fs * 8];                        \
            s16x8 pa1 = *(const s16x8*)&Ps[wid][fr][32 + fs * 8];                   \
            _Pragma("unroll")                                                       \
            for (int n = 0; n < 4; ++n) {                                           \
                s16x8 vb0 = *(const s16x8*)&Vs[BUF][n * 16 + fr][fs * 8];           \
                s16x8 vb1 = *(const s16x8*)&Vs[BUF][n * 16 + fr][32 + fs * 8];      \
                acc[n] = __builtin_amdgcn_mfma_f32_16x16x32_bf16(pa0, vb0, acc[n], 0, 0, 0); \
                acc[n] = __builtin_amdgcn_mfma_f32_16x16x32_bf16(pa1, vb1, acc[n], 0, 0, 0); \
            }                                                                       \
        }                                                                           \
    }

    for (int kt2 = 0; kt2 < 16; kt2 += 2) {
        AITER(kt2,     0, k0a, k0b, v0a, v0b);
        AITER(kt2 + 1, 1, k1a, k1b, v1a, v1b);
    }
#undef AITER

    const int bb = bh >> 4, hh = bh & 15;
    #pragma unroll
    for (int r = 0; r < 4; ++r) {
        const int q = q0 + wid * 16 + fs * 4 + r;
        const float il = invl_s[wid * 16 + fs * 4 + r];
        #pragma unroll
        for (int n = 0; n < 4; ++n)
            y[((long)(bb * 1024 + q) << 10) + hh * 64 + n * 16 + fr] = f2b(acc[n][r] * il);
    }
}

// ---------------- 2-phase GEMM with coalesced epilogues (R14-proven) --------
// EPI: 0=QKV scatter, 3=bias+resid->f32 (NT optional), 4=bias+GELU->bf16,
//      5=exp(s+mask) rowsum partials only
template <int BM, int BN, int EPI, bool NT = false>
__global__ __launch_bounds__(256)
void gemm_bt(const unsigned short* __restrict__ A,
             const unsigned short* __restrict__ Bm,
             int K, int lda, int ldb, int ldc,
             long sAz, long sBz,
             const float* __restrict__ bias,
             const float* __restrict__ resid,
             float* __restrict__ outF,
             unsigned short* __restrict__ outB) {
    constexpr int WM = BM / 2, WN = BN / 2;
    constexpr int FM = WM / 16, FN = WN / 16;
    constexpr int NTA = BM / 64, NTB = BN / 64;
    constexpr int LOADS = NTA + NTB;
    constexpr int STR = 136;
    constexpr int STRF = 132;
    __shared__ unsigned short shm[3 * BM * 32 + 3 * BN * 32];
    unsigned short* ldsA = shm;
    unsigned short* ldsB = shm + 3 * BM * 32;

    const int tid  = threadIdx.x;
    const int lane = tid & 63;
    const int wid  = tid >> 6;
    const int wr   = wid >> 1, wc = wid & 1;
    const int bz   = blockIdx.z;
    const int row0 = blockIdx.x * BM;
    const int col0 = blockIdx.y * BN;

    const unsigned short* Ab = A + (long)bz * sAz + (long)row0 * lda;
    const unsigned short* Bb = Bm + (long)bz * sBz + (long)col0 * ldb;

    const int nt = K >> 5;
    f32x4 acc[FM][FN] = {};
    const int fr = lane & 15;
    const int fk = (lane >> 4) * 8;

#define STAGE(T, BUF)                                                              \
    {                                                                              \
        const int k0s = (T) << 5;                                                  \
        _Pragma("unroll")                                                          \
        for (int i = 0; i < NTA; ++i) {                                            \
            int e = i * 2048 + wid * 512 + lane * 8;                               \
            gload16(Ab + k0s + (long)(e >> 5) * lda + (e & 31),                    \
                    &ldsA[(BUF) * BM * 32 + i * 2048 + wid * 512]);                \
        }                                                                          \
        _Pragma("unroll")                                                          \
        for (int i = 0; i < NTB; ++i) {                                            \
            int e = i * 2048 + wid * 512 + lane * 8;                               \
            gload16(Bb + k0s + (long)(e >> 5) * ldb + (e & 31),                    \
                    &ldsB[(BUF) * BN * 32 + i * 2048 + wid * 512]);                \
        }                                                                          \
    }

    STAGE(0, 0);
    if (nt > 1) STAGE(1, 1);

    for (int t = 0; t < nt; ++t) {
        const int buf = t % 3;
        if (t + 1 < nt) {
            if constexpr (LOADS == 2)      asm volatile("s_waitcnt vmcnt(2)" ::: "memory");
            else if constexpr (LOADS == 3) asm volatile("s_waitcnt vmcnt(3)" ::: "memory");
            else                           asm volatile("s_waitcnt vmcnt(4)" ::: "memory");
        } else {
            asm volatile("s_waitcnt vmcnt(0)" ::: "memory");
        }
        __syncthreads();
        if (t + 2 < nt) STAGE(t + 2, (t + 2) % 3);

        s16x8 af[FM], bfr[FN];
        #pragma unroll
        for (int m = 0; m < FM; ++m)
            af[m] = *(const s16x8*)&ldsA[buf * BM * 32 + (wr * WM + m * 16 + fr) * 32 + fk];
        #pragma unroll
        for (int n = 0; n < FN; ++n)
            bfr[n] = *(const s16x8*)&ldsB[buf * BN * 32 + (wc * WN + n * 16 + fr) * 32 + fk];
        #pragma unroll
        for (int m = 0; m < FM; ++m)
            #pragma unroll
            for (int n = 0; n < FN; ++n)
                acc[m][n] = __builtin_amdgcn_mfma_f32_16x16x32_bf16(af[m], bfr[n], acc[m][n], 0, 0, 0);
    }
#undef STAGE

    const int cj = lane & 15;
    const int r0 = (lane >> 4) * 4;

    if constexpr (EPI == 5) {
        #pragma unroll
        for (int m = 0; m < FM; ++m) {
            #pragma unroll
            for (int r = 0; r < 4; ++r) {
                const int grow = row0 + wr * WM + m * 16 + r0 + r;
                float rs = 0.0f;
                #pragma unroll
                for (int n = 0; n < FN; ++n) {
                    const int gcol = col0 + wc * WN + n * 16 + cj;
                    rs += __expf(acc[m][n][r] + resid[((long)grow << 10) + gcol]);
                }
                rs += __shfl_xor(rs, 1); rs += __shfl_xor(rs, 2);
                rs += __shfl_xor(rs, 4); rs += __shfl_xor(rs, 8);
                if (cj == 0)
                    outF[((((long)bz << 10) + grow) << 4) + blockIdx.y * 2 + wc] = rs;
            }
        }
    } else if constexpr (EPI == 0) {
        const int seg = col0 >> 10;
        const int bb = row0 >> 10;
        __syncthreads();
        if (seg < 2) {
            #pragma unroll
            for (int m = 0; m < FM; ++m)
                #pragma unroll
                for (int n = 0; n < FN; ++n)
                    #pragma unroll
                    for (int r = 0; r < 4; ++r) {
                        const int prow = wr * WM + m * 16 + r0 + r;
                        const int pcol = wc * WN + n * 16 + cj;
                        float v = acc[m][n][r] + bias[col0 + pcol];
                        if (seg == 0) v *= 0.125f;
                        shm[prow * STR + pcol] = f2b(v);
                    }
            __syncthreads();
            #pragma unroll
            for (int j = 0; j < 8; ++j) {
                const int idx = j * 2048 + tid * 8;
                const int row = idx >> 7, c = idx & 127;
                s16x8 val = *(const s16x8*)&shm[row * STR + c];
                const int t = (row0 + row) & 1023;
                const int hh = ((col0 & 1023) >> 6) + (c >> 6);
                const int dd = c & 63;
                const long bh = bb * 16 + hh;
                *(s16x8*)(outB + (seg == 1 ? 4194304 : 0) + (bh << 16) + (t << 6) + dd) = val;
            }
        } else {
            #pragma unroll
            for (int m = 0; m < FM; ++m)
                #pragma unroll
                for (int n = 0; n < FN; ++n)
                    #pragma unroll
                    for (int r = 0; r < 4; ++r) {
                        const int prow = wr * WM + m * 16 + r0 + r;
                        const int pcol = wc * WN + n * 16 + cj;
                        shm[pcol * 144 + prow] = f2b(acc[m][n][r] + bias[col0 + pcol]);
                    }
            __syncthreads();
            #pragma unroll
            for (int j = 0; j < 8; ++j) {
                const int idx = j * 2048 + tid * 8;
                const int ddl = idx >> 7, tl = idx & 127;
                s16x8 val = *(const s16x8*)&shm[ddl * 144 + tl];
                const int hh = ((col0 & 1023) >> 6) + (ddl >> 6);
                const int dd = ddl & 63;
                const int t = (row0 & 1023) + tl;
                const long bh = bb * 16 + hh;
                *(s16x8*)(outB + 8388608 + (bh << 16) + (dd << 10) + t) = val;
            }
        }
    } else if constexpr (EPI == 4) {
        __syncthreads();
        #pragma unroll
        for (int m = 0; m < FM; ++m)
            #pragma unroll
            for (int n = 0; n < FN; ++n)
                #pragma unroll
                for (int r = 0; r < 4; ++r) {
                    const int prow = wr * WM + m * 16 + r0 + r;
                    const int pcol = wc * WN + n * 16 + cj;
                    float u = acc[m][n][r] + bias[col0 + pcol];
                    shm[prow * STR + pcol] = f2b(gelu_t(u));
                }
        __syncthreads();
        #pragma unroll
        for (int j = 0; j < 8; ++j) {
            const int idx = j * 2048 + tid * 8;
            const int row = idx >> 7, c = idx & 127;
            s16x8 val = *(const s16x8*)&shm[row * STR + c];
            *(s16x8*)(outB + (long)(row0 + row) * ldc + col0 + c) = val;
        }
    } else {
        // EPI 3: bias + residual -> fp32, coalesced via fp32 LDS repack
        float* shf = (float*)shm;
        __syncthreads();
        #pragma unroll
        for (int m = 0; m < FM; ++m)
            #pragma unroll
            for (int n = 0; n < FN; ++n)
                #pragma unroll
                for (int r = 0; r < 4; ++r) {
                    const int prow = wr * WM + m * 16 + r0 + r;
                    const int pcol = wc * WN + n * 16 + cj;
                    shf[prow * STRF + pcol] = acc[m][n][r];
                }
        __syncthreads();
        #pragma unroll
        for (int j = 0; j < (BM * BN / 1024); ++j) {
            const int idx = j * 1024 + tid * 4;
            const int row = idx >> 7, c = idx & 127;
            f32x4 v = *(const f32x4*)&shf[row * STRF + c];
            const long gbase = ((long)(row0 + row) << 10) + col0 + c;
            f32x4 bv = *(const f32x4*)(bias + col0 + c);
            f32x4 rv = *(const f32x4*)(resid + gbase);
            #pragma unroll
            for (int q = 0; q < 4; ++q) v[q] += bv[q] + rv[q];
            if constexpr (NT) __builtin_nontemporal_store(v, (f32x4*)(outF + gbase));
            else              *(f32x4*)(outF + gbase) = v;
        }
    }
}

// ---------------- launch ----------------
extern "C" void kernel_launch(void* const* d_in, const int* in_sizes, int n_in,
                              void* d_out, int out_size, void* d_ws, size_t ws_size,
                              hipStream_t stream) {
    (void)in_sizes; (void)n_in; (void)out_size; (void)ws_size;
    const float* x     = (const float*)d_in[0];
    const float* mask  = (const float*)d_in[1];
    const float* ln1w  = (const float*)d_in[2];
    const float* ln1b  = (const float*)d_in[3];
    const float* wqkv  = (const float*)d_in[4];
    const float* bqkv  = (const float*)d_in[5];
    const float* wo    = (const float*)d_in[6];
    const float* bo    = (const float*)d_in[7];
    const float* ln2w  = (const float*)d_in[8];
    const float* ln2b  = (const float*)d_in[9];
    const float* wfc   = (const float*)d_in[10];
    const float* bfc   = (const float*)d_in[11];
    const float* wproj = (const float*)d_in[12];
    const float* bproj = (const float*)d_in[13];

    float* outx = (float*)d_out;                     // [4096,1024] fp32
    float* att  = (float*)d_out + 4194304;           // [64,1024,1024] fp32

    char* ws = (char*)d_ws;
    unsigned short* h_bf     = (unsigned short*)ws;  ws += (size_t)8  << 20;  // [4096,1024]
    unsigned short* wqkv_bf  = (unsigned short*)ws;  ws += (size_t)6  << 20;  // [3072,1024]
    unsigned short* wo_bf    = (unsigned short*)ws;  ws += (size_t)2  << 20;  // [1024,1024]
    unsigned short* wfc_bf   = (unsigned short*)ws;  ws += (size_t)8  << 20;  // [4096,1024]
    unsigned short* wproj_bf = (unsigned short*)ws;  ws += (size_t)8  << 20;  // [1024,4096]
    unsigned short* q_bf     = (unsigned short*)ws;  ws += (size_t)24 << 20;  // q,k,vT contiguous
    unsigned short* k_bf     = q_bf + 4194304;
    unsigned short* vT_bf    = q_bf + 8388608;
    unsigned short* y_bf     = (unsigned short*)ws;  ws += (size_t)8  << 20;  // [4096,1024]
    float*          x2       = (float*)ws;           ws += (size_t)16 << 20;  // [4096,1024] f32
    unsigned short* gelu_bf  = (unsigned short*)ws;  ws += (size_t)32 << 20;  // [4096,4096]
    float*          psum     = (float*)ws;           ws += (size_t)4  << 20;  // [64,1024,16] f32

    // cast weights + LN1 in one launch
    castln_kernel<<<16384, 256, 0, stream>>>(
        x, ln1w, ln1b, h_bf,
        wqkv, 786432, wo, 262144, wfc, 1048576, wproj, 1048576,
        wqkv_bf, wo_bf, wfc_bf, wproj_bf);

    // QKV: [4096,1024] x [3072,1024]^T -> q(scaled)/k/vT scatter (repacked stores)
    gemm_bt<128, 128, 0><<<dim3(32, 24, 1), 256, 0, stream>>>(
        h_bf, wqkv_bf, 1024, 1024, 1024, 0, 0, 0,
        bqkv, nullptr, nullptr, q_bf);

    // attn pass 1: per (b,h) rowsum partials only (no E store)
    gemm_bt<128, 128, 5><<<dim3(8, 8, 64), 256, 0, stream>>>(
        q_bf, k_bf, 64, 64, 64, 0, 65536, 65536,
        nullptr, mask, psum, nullptr);

    // attn pass 2: QK^T recompute + exp + att fp32 (NT) + PV -> y
    attn2<<<dim3(16, 64), 256, 0, stream>>>(
        q_bf, k_bf, vT_bf, mask, psum, att, y_bf);

    // W_o: [4096,1024] x [1024,1024]^T + b_o + x -> x2 (x2 re-read: temporal)
    gemm_bt<64, 128, 3><<<dim3(64, 8, 1), 256, 0, stream>>>(
        y_bf, wo_bf, 1024, 1024, 1024, 1024, 0, 0,
        bo, x, x2, nullptr);

    // LN2
    ln_kernel<<<4096, 256, 0, stream>>>(x2, ln2w, ln2b, h_bf);

    // FC + GELU: [4096,1024] x [4096,1024]^T -> gelu_bf (proven 2-phase path)
    gemm_bt<128, 128, 4><<<dim3(32, 32, 1), 256, 0, stream>>>(
        h_bf, wfc_bf, 1024, 1024, 1024, 4096, 0, 0,
        bfc, nullptr, nullptr, gelu_bf);

    // Proj: [4096,4096] x [1024,4096]^T + b_proj + x2 -> out (NT: never re-read)
    gemm_bt<64, 128, 3, true><<<dim3(64, 8, 1), 256, 0, stream>>>(
        gelu_bf, wproj_bf, 4096, 4096, 4096, 1024, 0, 0,
        bproj, x2, outx, nullptr);
}

// Round 17
// 393.548 us; speedup vs baseline: 1.7940x; 1.7940x over previous
//
#include <hip/hip_runtime.h>
#include <stdint.h>
#include <math.h>

// ---------------- types ----------------
typedef __attribute__((ext_vector_type(4))) float f32x4;
typedef __attribute__((ext_vector_type(8))) short s16x8;   // 8 x bf16 (4 VGPRs)
typedef __attribute__((ext_vector_type(4))) unsigned short u16x4;

__device__ __forceinline__ unsigned short f2b(float x) {
    union { float f; uint32_t u; } v; v.f = x;
    uint32_t r = v.u + 0x7FFFu + ((v.u >> 16) & 1u);   // round-to-nearest-even
    return (unsigned short)(r >> 16);
}
__device__ __forceinline__ float b2f(unsigned short u) {
    union { uint32_t u; float f; } v; v.u = (uint32_t)u << 16;
    return v.f;
}

__device__ __forceinline__ void gload16(const unsigned short* g, unsigned short* l) {
    __builtin_amdgcn_global_load_lds(
        (const __attribute__((address_space(1))) unsigned int*)(const void*)g,
        (__attribute__((address_space(3))) unsigned int*)(void*)l,
        16, 0, 0);
}

// tanh-form GELU (max abs dev from exact erf-GELU ~3e-4; budget 0.123)
__device__ __forceinline__ float gelu_t(float u) {
    float z = 0.7978845608f * (u + 0.044715f * u * u * u);
    float ez = __expf(2.0f * z);
    float th = 1.0f - 2.0f / (ez + 1.0f);
    return 0.5f * u * (1.0f + th);
}

// ---------------- fused cast(4 weights) + LN1 in one launch ----------------
__global__ __launch_bounds__(256) void castln_kernel(
        const float* __restrict__ x, const float* __restrict__ lw,
        const float* __restrict__ lb, unsigned short* __restrict__ lout,
        const float* __restrict__ a, int na, const float* __restrict__ b, int nb,
        const float* __restrict__ c, int nc, const float* __restrict__ d, int nd,
        unsigned short* __restrict__ oa, unsigned short* __restrict__ ob,
        unsigned short* __restrict__ oc, unsigned short* __restrict__ od) {
    const int tid = threadIdx.x;
    if (blockIdx.x < 4096) {
        const long row = blockIdx.x;
        f32x4 v = *(const f32x4*)(x + row * 1024 + tid * 4);
        float s  = v[0] + v[1] + v[2] + v[3];
        float sq = v[0]*v[0] + v[1]*v[1] + v[2]*v[2] + v[3]*v[3];
        #pragma unroll
        for (int off = 32; off; off >>= 1) {
            s  += __shfl_xor(s, off);
            sq += __shfl_xor(sq, off);
        }
        __shared__ float red[8];
        if ((tid & 63) == 0) { red[tid >> 6] = s; red[4 + (tid >> 6)] = sq; }
        __syncthreads();
        s  = red[0] + red[1] + red[2] + red[3];
        sq = red[4] + red[5] + red[6] + red[7];
        float mu  = s * (1.0f / 1024.0f);
        float var = sq * (1.0f / 1024.0f) - mu * mu;
        float rs  = rsqrtf(var + 1e-5f);
        f32x4 wv = *(const f32x4*)(lw + tid * 4);
        f32x4 bv = *(const f32x4*)(lb + tid * 4);
        u16x4 o;
        #pragma unroll
        for (int j = 0; j < 4; ++j) o[j] = f2b((v[j] - mu) * rs * wv[j] + bv[j]);
        *(u16x4*)(lout + row * 1024 + tid * 4) = o;
    } else {
        int i = (blockIdx.x - 4096) * 256 + tid;
        const float* src; unsigned short* dst; int off;
        if (i < na)                { src = a; dst = oa; off = i; }
        else if (i < na+nb)        { src = b; dst = ob; off = i - na; }
        else if (i < na+nb+nc)     { src = c; dst = oc; off = i - na - nb; }
        else if (i < na+nb+nc+nd)  { src = d; dst = od; off = i - na - nb - nc; }
        else return;
        f32x4 v = ((const f32x4*)src)[off];
        u16x4 o;
        #pragma unroll
        for (int j = 0; j < 4; ++j) o[j] = f2b(v[j]);
        ((u16x4*)dst)[off] = o;
    }
}

// ---------------- LayerNorm (standalone, LN2) ----------------
__global__ __launch_bounds__(256) void ln_kernel(const float* __restrict__ x,
                                                 const float* __restrict__ w,
                                                 const float* __restrict__ b,
                                                 unsigned short* __restrict__ out) {
    const long row = blockIdx.x;
    const int tid = threadIdx.x;
    f32x4 v = *(const f32x4*)(x + row * 1024 + tid * 4);
    float s  = v[0] + v[1] + v[2] + v[3];
    float sq = v[0]*v[0] + v[1]*v[1] + v[2]*v[2] + v[3]*v[3];
    #pragma unroll
    for (int off = 32; off; off >>= 1) {
        s  += __shfl_xor(s, off);
        sq += __shfl_xor(sq, off);
    }
    __shared__ float red[8];
    if ((tid & 63) == 0) { red[tid >> 6] = s; red[4 + (tid >> 6)] = sq; }
    __syncthreads();
    s  = red[0] + red[1] + red[2] + red[3];
    sq = red[4] + red[5] + red[6] + red[7];
    float mu  = s * (1.0f / 1024.0f);
    float var = sq * (1.0f / 1024.0f) - mu * mu;
    float rs  = rsqrtf(var + 1e-5f);
    f32x4 wv = *(const f32x4*)(w + tid * 4);
    f32x4 bv = *(const f32x4*)(b + tid * 4);
    u16x4 o;
    #pragma unroll
    for (int j = 0; j < 4; ++j) o[j] = f2b((v[j] - mu) * rs * wv[j] + bv[j]);
    *(u16x4*)(out + row * 1024 + tid * 4) = o;
}

// ---------------- fused attention pass 2 (R14-proven; temporal stores) ----------------
__global__ __launch_bounds__(256)
void attn2(const unsigned short* __restrict__ Qg,   // [64][1024][64] bf16, pre-scaled
           const unsigned short* __restrict__ Kg,   // [64][1024][64] bf16
           const unsigned short* __restrict__ Vt,   // [64][64][1024] bf16 (d-major)
           const float* __restrict__ mask,          // [1024][1024] f32
           const float* __restrict__ psum,          // [64][1024][16] partials
           float* __restrict__ att,                 // [64][1024][1024] fp32 out
           unsigned short* __restrict__ y) {        // [4096][1024] bf16 scatter
    __shared__ unsigned short Ks[2][64][72];
    __shared__ unsigned short Vs[2][64][72];
    __shared__ unsigned short Ps[4][16][72];
    __shared__ float invl_s[64];
    const int tid = threadIdx.x, lane = tid & 63, wid = tid >> 6;
    const int fr = lane & 15, fs = lane >> 4;
    const int bh = blockIdx.y, q0 = blockIdx.x * 64;

    if (tid < 64) {
        const float* p = psum + ((((long)bh << 10) + q0 + tid) << 4);
        f32x4 pa = *(const f32x4*)p,       pb = *(const f32x4*)(p + 4);
        f32x4 pc = *(const f32x4*)(p + 8), pd = *(const f32x4*)(p + 12);
        float s = (pa[0]+pa[1]+pa[2]+pa[3]) + (pb[0]+pb[1]+pb[2]+pb[3])
                + (pc[0]+pc[1]+pc[2]+pc[3]) + (pd[0]+pd[1]+pd[2]+pd[3]);
        invl_s[tid] = 1.0f / s;
    }

    const unsigned short* qp = Qg + ((long)bh << 16) + (long)(q0 + wid * 16 + fr) * 64 + fs * 8;
    const s16x8 aq0 = *(const s16x8*)qp;
    const s16x8 aq1 = *(const s16x8*)(qp + 32);

    const int srow = tid >> 2, scol = (tid & 3) * 16;
    const unsigned short* kbase = Kg + ((long)bh << 16) + (long)srow * 64 + scol;
    const unsigned short* vbase = Vt + ((long)bh << 16) + (long)srow * 1024 + scol;

    s16x8 k0a, k0b, v0a, v0b, k1a, k1b, v1a, v1b;
    k0a = *(const s16x8*)kbase;            k0b = *(const s16x8*)(kbase + 8);
    v0a = *(const s16x8*)vbase;            v0b = *(const s16x8*)(vbase + 8);
    k1a = *(const s16x8*)(kbase + 4096);   k1b = *(const s16x8*)(kbase + 4104);
    v1a = *(const s16x8*)(vbase + 64);     v1b = *(const s16x8*)(vbase + 72);

    f32x4 acc[4] = {};

#define AITER(KT, BUF, KA, KB, VA, VB)                                              \
    {                                                                               \
        *(s16x8*)&Ks[BUF][srow][scol]     = KA;                                     \
        *(s16x8*)&Ks[BUF][srow][scol + 8] = KB;                                     \
        *(s16x8*)&Vs[BUF][srow][scol]     = VA;                                     \
        *(s16x8*)&Vs[BUF][srow][scol + 8] = VB;                                     \
        __syncthreads();                                                            \
        if ((KT) + 2 < 16) {                                                        \
            const unsigned short* kp = kbase + (long)((KT) + 2) * 4096;             \
            const unsigned short* vp = vbase + ((KT) + 2) * 64;                     \
            KA = *(const s16x8*)kp;  KB = *(const s16x8*)(kp + 8);                  \
            VA = *(const s16x8*)vp;  VB = *(const s16x8*)(vp + 8);                  \
        }                                                                           \
        f32x4 s4[4];                                                                \
        _Pragma("unroll")                                                           \
        for (int n = 0; n < 4; ++n) {                                               \
            s16x8 b0 = *(const s16x8*)&Ks[BUF][n * 16 + fr][fs * 8];                \
            s16x8 b1 = *(const s16x8*)&Ks[BUF][n * 16 + fr][32 + fs * 8];           \
            f32x4 z = {};                                                           \
            z = __builtin_amdgcn_mfma_f32_16x16x32_bf16(aq0, b0, z, 0, 0, 0);       \
            z = __builtin_amdgcn_mfma_f32_16x16x32_bf16(aq1, b1, z, 0, 0, 0);       \
            s4[n] = z;                                                              \
        }                                                                           \
        _Pragma("unroll")                                                           \
        for (int r = 0; r < 4; ++r) {                                               \
            const long mb = ((long)(q0 + wid * 16 + fs * 4 + r) << 10) + (KT) * 64; \
            _Pragma("unroll")                                                       \
            for (int n = 0; n < 4; ++n) {                                           \
                float e = __expf(s4[n][r] + mask[mb + n * 16 + fr]);                \
                Ps[wid][fs * 4 + r][n * 16 + fr] = f2b(e);                          \
            }                                                                       \
        }                                                                           \
        {                                                                           \
            const float il = invl_s[srow];                                          \
            s16x8 p0 = *(const s16x8*)&Ps[wid][srow & 15][scol];                    \
            s16x8 p1 = *(const s16x8*)&Ps[wid][srow & 15][scol + 8];                \
            float* ap = att + ((long)bh << 20) + ((long)(q0 + srow) << 10)          \
                        + (KT) * 64 + scol;                                         \
            f32x4 o;                                                                \
            _Pragma("unroll") for (int j = 0; j < 4; ++j) o[j] = b2f((unsigned short)p0[j]) * il; \
            *(f32x4*)ap = o;                                                        \
            _Pragma("unroll") for (int j = 0; j < 4; ++j) o[j] = b2f((unsigned short)p0[4 + j]) * il; \
            *(f32x4*)(ap + 4) = o;                                                  \
            _Pragma("unroll") for (int j = 0; j < 4; ++j) o[j] = b2f((unsigned short)p1[j]) * il; \
            *(f32x4*)(ap + 8) = o;                                                  \
            _Pragma("unroll") for (int j = 0; j < 4; ++j) o[j] = b2f((unsigned short)p1[4 + j]) * il; \
            *(f32x4*)(ap + 12) = o;                                                 \
        }                                                                           \
        {                                                                           \
            s16x8 pa0 = *(const s16x8*)&Ps[wid][fr][fs * 8];                        \
            s16x8 pa1 = *(const s16x8*)&Ps[wid][fr][32 + fs * 8];                   \
            _Pragma("unroll")                                                       \
            for (int n = 0; n < 4; ++n) {                                           \
                s16x8 vb0 = *(const s16x8*)&Vs[BUF][n * 16 + fr][fs * 8];           \
                s16x8 vb1 = *(const s16x8*)&Vs[BUF][n * 16 + fr][32 + fs * 8];      \
                acc[n] = __builtin_amdgcn_mfma_f32_16x16x32_bf16(pa0, vb0, acc[n], 0, 0, 0); \
                acc[n] = __builtin_amdgcn_mfma_f32_16x16x32_bf16(pa1, vb1, acc[n], 0, 0, 0); \
            }                                                                       \
        }                                                                           \
    }

    for (int kt2 = 0; kt2 < 16; kt2 += 2) {
        AITER(kt2,     0, k0a, k0b, v0a, v0b);
        AITER(kt2 + 1, 1, k1a, k1b, v1a, v1b);
    }
#undef AITER

    const int bb = bh >> 4, hh = bh & 15;
    #pragma unroll
    for (int r = 0; r < 4; ++r) {
        const int q = q0 + wid * 16 + fs * 4 + r;
        const float il = invl_s[wid * 16 + fs * 4 + r];
        #pragma unroll
        for (int n = 0; n < 4; ++n)
            y[((long)(bb * 1024 + q) << 10) + hh * 64 + n * 16 + fr] = f2b(acc[n][r] * il);
    }
}

// ---------------- 2-phase GEMM with coalesced epilogues (R14-proven) --------
// EPI: 0=QKV scatter, 3=bias+resid->f32, 4=bias+GELU->bf16,
//      5=exp(s+mask) rowsum partials only
template <int BM, int BN, int EPI>
__global__ __launch_bounds__(256)
void gemm_bt(const unsigned short* __restrict__ A,
             const unsigned short* __restrict__ Bm,
             int K, int lda, int ldb, int ldc,
             long sAz, long sBz,
             const float* __restrict__ bias,
             const float* __restrict__ resid,
             float* __restrict__ outF,
             unsigned short* __restrict__ outB) {
    constexpr int WM = BM / 2, WN = BN / 2;
    constexpr int FM = WM / 16, FN = WN / 16;
    constexpr int NTA = BM / 64, NTB = BN / 64;
    constexpr int LOADS = NTA + NTB;
    constexpr int STR = 136;
    constexpr int STRF = 132;
    __shared__ unsigned short shm[3 * BM * 32 + 3 * BN * 32];
    unsigned short* ldsA = shm;
    unsigned short* ldsB = shm + 3 * BM * 32;

    const int tid  = threadIdx.x;
    const int lane = tid & 63;
    const int wid  = tid >> 6;
    const int wr   = wid >> 1, wc = wid & 1;
    const int bz   = blockIdx.z;
    const int row0 = blockIdx.x * BM;
    const int col0 = blockIdx.y * BN;

    const unsigned short* Ab = A + (long)bz * sAz + (long)row0 * lda;
    const unsigned short* Bb = Bm + (long)bz * sBz + (long)col0 * ldb;

    const int nt = K >> 5;
    f32x4 acc[FM][FN] = {};
    const int fr = lane & 15;
    const int fk = (lane >> 4) * 8;

#define STAGE(T, BUF)                                                              \
    {                                                                              \
        const int k0s = (T) << 5;                                                  \
        _Pragma("unroll")                                                          \
        for (int i = 0; i < NTA; ++i) {                                            \
            int e = i * 2048 + wid * 512 + lane * 8;                               \
            gload16(Ab + k0s + (long)(e >> 5) * lda + (e & 31),                    \
                    &ldsA[(BUF) * BM * 32 + i * 2048 + wid * 512]);                \
        }                                                                          \
        _Pragma("unroll")                                                          \
        for (int i = 0; i < NTB; ++i) {                                            \
            int e = i * 2048 + wid * 512 + lane * 8;                               \
            gload16(Bb + k0s + (long)(e >> 5) * ldb + (e & 31),                    \
                    &ldsB[(BUF) * BN * 32 + i * 2048 + wid * 512]);                \
        }                                                                          \
    }

    STAGE(0, 0);
    if (nt > 1) STAGE(1, 1);

    for (int t = 0; t < nt; ++t) {
        const int buf = t % 3;
        if (t + 1 < nt) {
            if constexpr (LOADS == 2)      asm volatile("s_waitcnt vmcnt(2)" ::: "memory");
            else if constexpr (LOADS == 3) asm volatile("s_waitcnt vmcnt(3)" ::: "memory");
            else                           asm volatile("s_waitcnt vmcnt(4)" ::: "memory");
        } else {
            asm volatile("s_waitcnt vmcnt(0)" ::: "memory");
        }
        __syncthreads();
        if (t + 2 < nt) STAGE(t + 2, (t + 2) % 3);

        s16x8 af[FM], bfr[FN];
        #pragma unroll
        for (int m = 0; m < FM; ++m)
            af[m] = *(const s16x8*)&ldsA[buf * BM * 32 + (wr * WM + m * 16 + fr) * 32 + fk];
        #pragma unroll
        for (int n = 0; n < FN; ++n)
            bfr[n] = *(const s16x8*)&ldsB[buf * BN * 32 + (wc * WN + n * 16 + fr) * 32 + fk];
        #pragma unroll
        for (int m = 0; m < FM; ++m)
            #pragma unroll
            for (int n = 0; n < FN; ++n)
                acc[m][n] = __builtin_amdgcn_mfma_f32_16x16x32_bf16(af[m], bfr[n], acc[m][n], 0, 0, 0);
    }
#undef STAGE

    const int cj = lane & 15;
    const int r0 = (lane >> 4) * 4;

    if constexpr (EPI == 5) {
        #pragma unroll
        for (int m = 0; m < FM; ++m) {
            #pragma unroll
            for (int r = 0; r < 4; ++r) {
                const int grow = row0 + wr * WM + m * 16 + r0 + r;
                float rs = 0.0f;
                #pragma unroll
                for (int n = 0; n < FN; ++n) {
                    const int gcol = col0 + wc * WN + n * 16 + cj;
                    rs += __expf(acc[m][n][r] + resid[((long)grow << 10) + gcol]);
                }
                rs += __shfl_xor(rs, 1); rs += __shfl_xor(rs, 2);
                rs += __shfl_xor(rs, 4); rs += __shfl_xor(rs, 8);
                if (cj == 0)
                    outF[((((long)bz << 10) + grow) << 4) + blockIdx.y * 2 + wc] = rs;
            }
        }
    } else if constexpr (EPI == 0) {
        const int seg = col0 >> 10;
        const int bb = row0 >> 10;
        __syncthreads();
        if (seg < 2) {
            #pragma unroll
            for (int m = 0; m < FM; ++m)
                #pragma unroll
                for (int n = 0; n < FN; ++n)
                    #pragma unroll
                    for (int r = 0; r < 4; ++r) {
                        const int prow = wr * WM + m * 16 + r0 + r;
                        const int pcol = wc * WN + n * 16 + cj;
                        float v = acc[m][n][r] + bias[col0 + pcol];
                        if (seg == 0) v *= 0.125f;
                        shm[prow * STR + pcol] = f2b(v);
                    }
            __syncthreads();
            #pragma unroll
            for (int j = 0; j < 8; ++j) {
                const int idx = j * 2048 + tid * 8;
                const int row = idx >> 7, c = idx & 127;
                s16x8 val = *(const s16x8*)&shm[row * STR + c];
                const int t = (row0 + row) & 1023;
                const int hh = ((col0 & 1023) >> 6) + (c >> 6);
                const int dd = c & 63;
                const long bh = bb * 16 + hh;
                *(s16x8*)(outB + (seg == 1 ? 4194304 : 0) + (bh << 16) + (t << 6) + dd) = val;
            }
        } else {
            #pragma unroll
            for (int m = 0; m < FM; ++m)
                #pragma unroll
                for (int n = 0; n < FN; ++n)
                    #pragma unroll
                    for (int r = 0; r < 4; ++r) {
                        const int prow = wr * WM + m * 16 + r0 + r;
                        const int pcol = wc * WN + n * 16 + cj;
                        shm[pcol * 144 + prow] = f2b(acc[m][n][r] + bias[col0 + pcol]);
                    }
            __syncthreads();
            #pragma unroll
            for (int j = 0; j < 8; ++j) {
                const int idx = j * 2048 + tid * 8;
                const int ddl = idx >> 7, tl = idx & 127;
                s16x8 val = *(const s16x8*)&shm[ddl * 144 + tl];
                const int hh = ((col0 & 1023) >> 6) + (ddl >> 6);
                const int dd = ddl & 63;
                const int t = (row0 & 1023) + tl;
                const long bh = bb * 16 + hh;
                *(s16x8*)(outB + 8388608 + (bh << 16) + (dd << 10) + t) = val;
            }
        }
    } else if constexpr (EPI == 4) {
        __syncthreads();
        #pragma unroll
        for (int m = 0; m < FM; ++m)
            #pragma unroll
            for (int n = 0; n < FN; ++n)
                #pragma unroll
                for (int r = 0; r < 4; ++r) {
                    const int prow = wr * WM + m * 16 + r0 + r;
                    const int pcol = wc * WN + n * 16 + cj;
                    float u = acc[m][n][r] + bias[col0 + pcol];
                    shm[prow * STR + pcol] = f2b(gelu_t(u));
                }
        __syncthreads();
        #pragma unroll
        for (int j = 0; j < 8; ++j) {
            const int idx = j * 2048 + tid * 8;
            const int row = idx >> 7, c = idx & 127;
            s16x8 val = *(const s16x8*)&shm[row * STR + c];
            *(s16x8*)(outB + (long)(row0 + row) * ldc + col0 + c) = val;
        }
    } else {
        // EPI 3: bias + residual -> fp32, coalesced via fp32 LDS repack
        float* shf = (float*)shm;
        __syncthreads();
        #pragma unroll
        for (int m = 0; m < FM; ++m)
            #pragma unroll
            for (int n = 0; n < FN; ++n)
                #pragma unroll
                for (int r = 0; r < 4; ++r) {
                    const int prow = wr * WM + m * 16 + r0 + r;
                    const int pcol = wc * WN + n * 16 + cj;
                    shf[prow * STRF + pcol] = acc[m][n][r];
                }
        __syncthreads();
        #pragma unroll
        for (int j = 0; j < (BM * BN / 1024); ++j) {
            const int idx = j * 1024 + tid * 4;
            const int row = idx >> 7, c = idx & 127;
            f32x4 v = *(const f32x4*)&shf[row * STRF + c];
            const long gbase = ((long)(row0 + row) << 10) + col0 + c;
            f32x4 bv = *(const f32x4*)(bias + col0 + c);
            f32x4 rv = *(const f32x4*)(resid + gbase);
            #pragma unroll
            for (int q = 0; q < 4; ++q) v[q] += bv[q] + rv[q];
            *(f32x4*)(outF + gbase) = v;
        }
    }
}

// ---------------- launch ----------------
extern "C" void kernel_launch(void* const* d_in, const int* in_sizes, int n_in,
                              void* d_out, int out_size, void* d_ws, size_t ws_size,
                              hipStream_t stream) {
    (void)in_sizes; (void)n_in; (void)out_size; (void)ws_size;
    const float* x     = (const float*)d_in[0];
    const float* mask  = (const float*)d_in[1];
    const float* ln1w  = (const float*)d_in[2];
    const float* ln1b  = (const float*)d_in[3];
    const float* wqkv  = (const float*)d_in[4];
    const float* bqkv  = (const float*)d_in[5];
    const float* wo    = (const float*)d_in[6];
    const float* bo    = (const float*)d_in[7];
    const float* ln2w  = (const float*)d_in[8];
    const float* ln2b  = (const float*)d_in[9];
    const float* wfc   = (const float*)d_in[10];
    const float* bfc   = (const float*)d_in[11];
    const float* wproj = (const float*)d_in[12];
    const float* bproj = (const float*)d_in[13];

    float* outx = (float*)d_out;                     // [4096,1024] fp32
    float* att  = (float*)d_out + 4194304;           // [64,1024,1024] fp32

    char* ws = (char*)d_ws;
    unsigned short* h_bf     = (unsigned short*)ws;  ws += (size_t)8  << 20;  // [4096,1024]
    unsigned short* wqkv_bf  = (unsigned short*)ws;  ws += (size_t)6  << 20;  // [3072,1024]
    unsigned short* wo_bf    = (unsigned short*)ws;  ws += (size_t)2  << 20;  // [1024,1024]
    unsigned short* wfc_bf   = (unsigned short*)ws;  ws += (size_t)8  << 20;  // [4096,1024]
    unsigned short* wproj_bf = (unsigned short*)ws;  ws += (size_t)8  << 20;  // [1024,4096]
    unsigned short* q_bf     = (unsigned short*)ws;  ws += (size_t)24 << 20;  // q,k,vT contiguous
    unsigned short* k_bf     = q_bf + 4194304;
    unsigned short* vT_bf    = q_bf + 8388608;
    unsigned short* y_bf     = (unsigned short*)ws;  ws += (size_t)8  << 20;  // [4096,1024]
    float*          x2       = (float*)ws;           ws += (size_t)16 << 20;  // [4096,1024] f32
    unsigned short* gelu_bf  = (unsigned short*)ws;  ws += (size_t)32 << 20;  // [4096,4096]
    float*          psum     = (float*)ws;           ws += (size_t)4  << 20;  // [64,1024,16] f32

    // cast weights + LN1 in one launch
    castln_kernel<<<16384, 256, 0, stream>>>(
        x, ln1w, ln1b, h_bf,
        wqkv, 786432, wo, 262144, wfc, 1048576, wproj, 1048576,
        wqkv_bf, wo_bf, wfc_bf, wproj_bf);

    // QKV: [4096,1024] x [3072,1024]^T -> q(scaled)/k/vT scatter (repacked stores)
    gemm_bt<128, 128, 0><<<dim3(32, 24, 1), 256, 0, stream>>>(
        h_bf, wqkv_bf, 1024, 1024, 1024, 0, 0, 0,
        bqkv, nullptr, nullptr, q_bf);

    // attn pass 1: per (b,h) rowsum partials only (no E store)
    gemm_bt<128, 128, 5><<<dim3(8, 8, 64), 256, 0, stream>>>(
        q_bf, k_bf, 64, 64, 64, 0, 65536, 65536,
        nullptr, mask, psum, nullptr);

    // attn pass 2: QK^T recompute + exp + att fp32 + PV -> y
    attn2<<<dim3(16, 64), 256, 0, stream>>>(
        q_bf, k_bf, vT_bf, mask, psum, att, y_bf);

    // W_o: [4096,1024] x [1024,1024]^T + b_o + x -> x2
    gemm_bt<64, 128, 3><<<dim3(64, 8, 1), 256, 0, stream>>>(
        y_bf, wo_bf, 1024, 1024, 1024, 1024, 0, 0,
        bo, x, x2, nullptr);

    // LN2
    ln_kernel<<<4096, 256, 0, stream>>>(x2, ln2w, ln2b, h_bf);

    // FC + GELU: [4096,1024] x [4096,1024]^T -> gelu_bf
    gemm_bt<128, 128, 4><<<dim3(32, 32, 1), 256, 0, stream>>>(
        h_bf, wfc_bf, 1024, 1024, 1024, 4096, 0, 0,
        bfc, nullptr, nullptr, gelu_bf);

    // Proj: [4096,4096] x [1024,4096]^T + b_proj + x2 -> out
    gemm_bt<64, 128, 3><<<dim3(64, 8, 1), 256, 0, stream>>>(
        gelu_bf, wproj_bf, 4096, 4096, 4096, 1024, 0, 0,
        bproj, x2, outx, nullptr);
}

// Round 18
// 359.146 us; speedup vs baseline: 1.9658x; 1.0958x over previous
//
#include <hip/hip_runtime.h>
#include <stdint.h>
#include <math.h>

// ---------------- types ----------------
typedef __attribute__((ext_vector_type(4))) float f32x4;
typedef __attribute__((ext_vector_type(8))) short s16x8;   // 8 x bf16 (4 VGPRs)
typedef __attribute__((ext_vector_type(4))) unsigned short u16x4;

__device__ __forceinline__ unsigned short f2b(float x) {
    union { float f; uint32_t u; } v; v.f = x;
    uint32_t r = v.u + 0x7FFFu + ((v.u >> 16) & 1u);   // round-to-nearest-even
    return (unsigned short)(r >> 16);
}
__device__ __forceinline__ float b2f(unsigned short u) {
    union { uint32_t u; float f; } v; v.u = (uint32_t)u << 16;
    return v.f;
}

__device__ __forceinline__ void gload16(const unsigned short* g, unsigned short* l) {
    __builtin_amdgcn_global_load_lds(
        (const __attribute__((address_space(1))) unsigned int*)(const void*)g,
        (__attribute__((address_space(3))) unsigned int*)(void*)l,
        16, 0, 0);
}

// tanh-form GELU (max abs dev from exact erf-GELU ~3e-4; budget 0.123)
__device__ __forceinline__ float gelu_t(float u) {
    float z = 0.7978845608f * (u + 0.044715f * u * u * u);
    float ez = __expf(2.0f * z);
    float th = 1.0f - 2.0f / (ez + 1.0f);
    return 0.5f * u * (1.0f + th);
}

// ---------------- fused cast(4 weights) + LN1 in one launch ----------------
__global__ __launch_bounds__(256) void castln_kernel(
        const float* __restrict__ x, const float* __restrict__ lw,
        const float* __restrict__ lb, unsigned short* __restrict__ lout,
        const float* __restrict__ a, int na, const float* __restrict__ b, int nb,
        const float* __restrict__ c, int nc, const float* __restrict__ d, int nd,
        unsigned short* __restrict__ oa, unsigned short* __restrict__ ob,
        unsigned short* __restrict__ oc, unsigned short* __restrict__ od) {
    const int tid = threadIdx.x;
    if (blockIdx.x < 4096) {
        const long row = blockIdx.x;
        f32x4 v = *(const f32x4*)(x + row * 1024 + tid * 4);
        float s  = v[0] + v[1] + v[2] + v[3];
        float sq = v[0]*v[0] + v[1]*v[1] + v[2]*v[2] + v[3]*v[3];
        #pragma unroll
        for (int off = 32; off; off >>= 1) {
            s  += __shfl_xor(s, off);
            sq += __shfl_xor(sq, off);
        }
        __shared__ float red[8];
        if ((tid & 63) == 0) { red[tid >> 6] = s; red[4 + (tid >> 6)] = sq; }
        __syncthreads();
        s  = red[0] + red[1] + red[2] + red[3];
        sq = red[4] + red[5] + red[6] + red[7];
        float mu  = s * (1.0f / 1024.0f);
        float var = sq * (1.0f / 1024.0f) - mu * mu;
        float rs  = rsqrtf(var + 1e-5f);
        f32x4 wv = *(const f32x4*)(lw + tid * 4);
        f32x4 bv = *(const f32x4*)(lb + tid * 4);
        u16x4 o;
        #pragma unroll
        for (int j = 0; j < 4; ++j) o[j] = f2b((v[j] - mu) * rs * wv[j] + bv[j]);
        *(u16x4*)(lout + row * 1024 + tid * 4) = o;
    } else {
        int i = (blockIdx.x - 4096) * 256 + tid;
        const float* src; unsigned short* dst; int off;
        if (i < na)                { src = a; dst = oa; off = i; }
        else if (i < na+nb)        { src = b; dst = ob; off = i - na; }
        else if (i < na+nb+nc)     { src = c; dst = oc; off = i - na - nb; }
        else if (i < na+nb+nc+nd)  { src = d; dst = od; off = i - na - nb - nc; }
        else return;
        f32x4 v = ((const f32x4*)src)[off];
        u16x4 o;
        #pragma unroll
        for (int j = 0; j < 4; ++j) o[j] = f2b(v[j]);
        ((u16x4*)dst)[off] = o;
    }
}

// ---------------- LayerNorm (standalone, LN2) ----------------
__global__ __launch_bounds__(256) void ln_kernel(const float* __restrict__ x,
                                                 const float* __restrict__ w,
                                                 const float* __restrict__ b,
                                                 unsigned short* __restrict__ out) {
    const long row = blockIdx.x;
    const int tid = threadIdx.x;
    f32x4 v = *(const f32x4*)(x + row * 1024 + tid * 4);
    float s  = v[0] + v[1] + v[2] + v[3];
    float sq = v[0]*v[0] + v[1]*v[1] + v[2]*v[2] + v[3]*v[3];
    #pragma unroll
    for (int off = 32; off; off >>= 1) {
        s  += __shfl_xor(s, off);
        sq += __shfl_xor(sq, off);
    }
    __shared__ float red[8];
    if ((tid & 63) == 0) { red[tid >> 6] = s; red[4 + (tid >> 6)] = sq; }
    __syncthreads();
    s  = red[0] + red[1] + red[2] + red[3];
    sq = red[4] + red[5] + red[6] + red[7];
    float mu  = s * (1.0f / 1024.0f);
    float var = sq * (1.0f / 1024.0f) - mu * mu;
    float rs  = rsqrtf(var + 1e-5f);
    f32x4 wv = *(const f32x4*)(w + tid * 4);
    f32x4 bv = *(const f32x4*)(b + tid * 4);
    u16x4 o;
    #pragma unroll
    for (int j = 0; j < 4; ++j) o[j] = f2b((v[j] - mu) * rs * wv[j] + bv[j]);
    *(u16x4*)(out + row * 1024 + tid * 4) = o;
}

// ---------------- fused attention (single kernel): rowsums + att fp32 + PV ----------------
// block: 64 q-rows x one bh, 4 waves. Pass A: QK^T -> exp -> rowsums (K-only staging).
// Pass B: QK^T recompute -> exp -> att fp32 (normalized) + P bf16 -> PV MFMA -> y.
__global__ __launch_bounds__(256)
void attn_all(const unsigned short* __restrict__ Qg,   // [64][1024][64] bf16, pre-scaled
              const unsigned short* __restrict__ Kg,   // [64][1024][64] bf16
              const unsigned short* __restrict__ Vt,   // [64][64][1024] bf16 (d-major)
              const float* __restrict__ mask,          // [1024][1024] f32
              float* __restrict__ att,                 // [64][1024][1024] fp32 out
              unsigned short* __restrict__ y) {        // [4096][1024] bf16 scatter
    __shared__ unsigned short Ks[2][64][72];
    __shared__ unsigned short Vs[2][64][72];
    __shared__ unsigned short Ps[4][16][72];
    __shared__ float invl_s[64];
    const int tid = threadIdx.x, lane = tid & 63, wid = tid >> 6;
    const int fr = lane & 15, fs = lane >> 4;
    const int bh = blockIdx.y, q0 = blockIdx.x * 64;

    const unsigned short* qp = Qg + ((long)bh << 16) + (long)(q0 + wid * 16 + fr) * 64 + fs * 8;
    const s16x8 aq0 = *(const s16x8*)qp;
    const s16x8 aq1 = *(const s16x8*)(qp + 32);

    const int srow = tid >> 2, scol = (tid & 3) * 16;
    const unsigned short* kbase = Kg + ((long)bh << 16) + (long)srow * 64 + scol;
    const unsigned short* vbase = Vt + ((long)bh << 16) + (long)srow * 1024 + scol;

    // ================= pass A: rowsums =================
    float rs4[4] = {0.0f, 0.0f, 0.0f, 0.0f};
    {
        s16x8 ka0 = *(const s16x8*)kbase,          kc0 = *(const s16x8*)(kbase + 8);
        s16x8 ka1 = *(const s16x8*)(kbase + 4096), kc1 = *(const s16x8*)(kbase + 4104);

#define PITER(KT, BUF, KA, KB)                                                      \
        {                                                                           \
            *(s16x8*)&Ks[BUF][srow][scol]     = KA;                                 \
            *(s16x8*)&Ks[BUF][srow][scol + 8] = KB;                                 \
            __syncthreads();                                                        \
            if ((KT) + 2 < 16) {                                                    \
                const unsigned short* kp = kbase + (long)((KT) + 2) * 4096;         \
                KA = *(const s16x8*)kp;  KB = *(const s16x8*)(kp + 8);              \
            }                                                                       \
            _Pragma("unroll")                                                       \
            for (int n = 0; n < 4; ++n) {                                           \
                s16x8 b0 = *(const s16x8*)&Ks[BUF][n * 16 + fr][fs * 8];            \
                s16x8 b1 = *(const s16x8*)&Ks[BUF][n * 16 + fr][32 + fs * 8];       \
                f32x4 z = {};                                                       \
                z = __builtin_amdgcn_mfma_f32_16x16x32_bf16(aq0, b0, z, 0, 0, 0);   \
                z = __builtin_amdgcn_mfma_f32_16x16x32_bf16(aq1, b1, z, 0, 0, 0);   \
                _Pragma("unroll")                                                   \
                for (int r = 0; r < 4; ++r) {                                       \
                    const long mb = ((long)(q0 + wid * 16 + fs * 4 + r) << 10)      \
                                    + (KT) * 64;                                    \
                    rs4[r] += __expf(z[r] + mask[mb + n * 16 + fr]);                \
                }                                                                   \
            }                                                                       \
        }

        for (int kt2 = 0; kt2 < 16; kt2 += 2) {
            PITER(kt2,     0, ka0, kc0);
            PITER(kt2 + 1, 1, ka1, kc1);
        }
#undef PITER
    }
    #pragma unroll
    for (int r = 0; r < 4; ++r) {
        float t = rs4[r];
        t += __shfl_xor(t, 1); t += __shfl_xor(t, 2);
        t += __shfl_xor(t, 4); t += __shfl_xor(t, 8);
        if (fr == 0) invl_s[wid * 16 + fs * 4 + r] = 1.0f / t;
    }

    // ================= pass B: att write + PV =================
    s16x8 k0a, k0b, v0a, v0b, k1a, k1b, v1a, v1b;
    k0a = *(const s16x8*)kbase;            k0b = *(const s16x8*)(kbase + 8);
    v0a = *(const s16x8*)vbase;            v0b = *(const s16x8*)(vbase + 8);
    k1a = *(const s16x8*)(kbase + 4096);   k1b = *(const s16x8*)(kbase + 4104);
    v1a = *(const s16x8*)(vbase + 64);     v1b = *(const s16x8*)(vbase + 72);

    f32x4 acc[4] = {};

#define AITER(KT, BUF, KA, KB, VA, VB)                                              \
    {                                                                               \
        *(s16x8*)&Ks[BUF][srow][scol]     = KA;                                     \
        *(s16x8*)&Ks[BUF][srow][scol + 8] = KB;                                     \
        *(s16x8*)&Vs[BUF][srow][scol]     = VA;                                     \
        *(s16x8*)&Vs[BUF][srow][scol + 8] = VB;                                     \
        __syncthreads();                                                            \
        if ((KT) + 2 < 16) {                                                        \
            const unsigned short* kp = kbase + (long)((KT) + 2) * 4096;             \
            const unsigned short* vp = vbase + ((KT) + 2) * 64;                     \
            KA = *(const s16x8*)kp;  KB = *(const s16x8*)(kp + 8);                  \
            VA = *(const s16x8*)vp;  VB = *(const s16x8*)(vp + 8);                  \
        }                                                                           \
        f32x4 s4[4];                                                                \
        _Pragma("unroll")                                                           \
        for (int n = 0; n < 4; ++n) {                                               \
            s16x8 b0 = *(const s16x8*)&Ks[BUF][n * 16 + fr][fs * 8];                \
            s16x8 b1 = *(const s16x8*)&Ks[BUF][n * 16 + fr][32 + fs * 8];           \
            f32x4 z = {};                                                           \
            z = __builtin_amdgcn_mfma_f32_16x16x32_bf16(aq0, b0, z, 0, 0, 0);       \
            z = __builtin_amdgcn_mfma_f32_16x16x32_bf16(aq1, b1, z, 0, 0, 0);       \
            s4[n] = z;                                                              \
        }                                                                           \
        _Pragma("unroll")                                                           \
        for (int r = 0; r < 4; ++r) {                                               \
            const long mb = ((long)(q0 + wid * 16 + fs * 4 + r) << 10) + (KT) * 64; \
            _Pragma("unroll")                                                       \
            for (int n = 0; n < 4; ++n) {                                           \
                float e = __expf(s4[n][r] + mask[mb + n * 16 + fr]);                \
                Ps[wid][fs * 4 + r][n * 16 + fr] = f2b(e);                          \
            }                                                                       \
        }                                                                           \
        {                                                                           \
            const float il = invl_s[srow];                                          \
            s16x8 p0 = *(const s16x8*)&Ps[wid][srow & 15][scol];                    \
            s16x8 p1 = *(const s16x8*)&Ps[wid][srow & 15][scol + 8];                \
            float* ap = att + ((long)bh << 20) + ((long)(q0 + srow) << 10)          \
                        + (KT) * 64 + scol;                                         \
            f32x4 o;                                                                \
            _Pragma("unroll") for (int j = 0; j < 4; ++j) o[j] = b2f((unsigned short)p0[j]) * il; \
            *(f32x4*)ap = o;                                                        \
            _Pragma("unroll") for (int j = 0; j < 4; ++j) o[j] = b2f((unsigned short)p0[4 + j]) * il; \
            *(f32x4*)(ap + 4) = o;                                                  \
            _Pragma("unroll") for (int j = 0; j < 4; ++j) o[j] = b2f((unsigned short)p1[j]) * il; \
            *(f32x4*)(ap + 8) = o;                                                  \
            _Pragma("unroll") for (int j = 0; j < 4; ++j) o[j] = b2f((unsigned short)p1[4 + j]) * il; \
            *(f32x4*)(ap + 12) = o;                                                 \
        }                                                                           \
        {                                                                           \
            s16x8 pa0 = *(const s16x8*)&Ps[wid][fr][fs * 8];                        \
            s16x8 pa1 = *(const s16x8*)&Ps[wid][fr][32 + fs * 8];                   \
            _Pragma("unroll")                                                       \
            for (int n = 0; n < 4; ++n) {                                           \
                s16x8 vb0 = *(const s16x8*)&Vs[BUF][n * 16 + fr][fs * 8];           \
                s16x8 vb1 = *(const s16x8*)&Vs[BUF][n * 16 + fr][32 + fs * 8];      \
                acc[n] = __builtin_amdgcn_mfma_f32_16x16x32_bf16(pa0, vb0, acc[n], 0, 0, 0); \
                acc[n] = __builtin_amdgcn_mfma_f32_16x16x32_bf16(pa1, vb1, acc[n], 0, 0, 0); \
            }                                                                       \
        }                                                                           \
    }

    for (int kt2 = 0; kt2 < 16; kt2 += 2) {
        AITER(kt2,     0, k0a, k0b, v0a, v0b);
        AITER(kt2 + 1, 1, k1a, k1b, v1a, v1b);
    }
#undef AITER

    const int bb = bh >> 4, hh = bh & 15;
    #pragma unroll
    for (int r = 0; r < 4; ++r) {
        const int q = q0 + wid * 16 + fs * 4 + r;
        const float il = invl_s[wid * 16 + fs * 4 + r];
        #pragma unroll
        for (int n = 0; n < 4; ++n)
            y[((long)(bb * 1024 + q) << 10) + hh * 64 + n * 16 + fr] = f2b(acc[n][r] * il);
    }
}

// ---------------- 2-phase GEMM with coalesced epilogues (R14-proven) --------
// EPI: 0=QKV scatter, 3=bias+resid->f32, 4=bias+GELU->bf16
template <int BM, int BN, int EPI>
__global__ __launch_bounds__(256)
void gemm_bt(const unsigned short* __restrict__ A,
             const unsigned short* __restrict__ Bm,
             int K, int lda, int ldb, int ldc,
             long sAz, long sBz,
             const float* __restrict__ bias,
             const float* __restrict__ resid,
             float* __restrict__ outF,
             unsigned short* __restrict__ outB) {
    constexpr int WM = BM / 2, WN = BN / 2;
    constexpr int FM = WM / 16, FN = WN / 16;
    constexpr int NTA = BM / 64, NTB = BN / 64;
    constexpr int LOADS = NTA + NTB;
    constexpr int STR = 136;
    constexpr int STRF = 132;
    __shared__ unsigned short shm[3 * BM * 32 + 3 * BN * 32];
    unsigned short* ldsA = shm;
    unsigned short* ldsB = shm + 3 * BM * 32;

    const int tid  = threadIdx.x;
    const int lane = tid & 63;
    const int wid  = tid >> 6;
    const int wr   = wid >> 1, wc = wid & 1;
    const int bz   = blockIdx.z;
    const int row0 = blockIdx.x * BM;
    const int col0 = blockIdx.y * BN;

    const unsigned short* Ab = A + (long)bz * sAz + (long)row0 * lda;
    const unsigned short* Bb = Bm + (long)bz * sBz + (long)col0 * ldb;

    const int nt = K >> 5;
    f32x4 acc[FM][FN] = {};
    const int fr = lane & 15;
    const int fk = (lane >> 4) * 8;

#define STAGE(T, BUF)                                                              \
    {                                                                              \
        const int k0s = (T) << 5;                                                  \
        _Pragma("unroll")                                                          \
        for (int i = 0; i < NTA; ++i) {                                            \
            int e = i * 2048 + wid * 512 + lane * 8;                               \
            gload16(Ab + k0s + (long)(e >> 5) * lda + (e & 31),                    \
                    &ldsA[(BUF) * BM * 32 + i * 2048 + wid * 512]);                \
        }                                                                          \
        _Pragma("unroll")                                                          \
        for (int i = 0; i < NTB; ++i) {                                            \
            int e = i * 2048 + wid * 512 + lane * 8;                               \
            gload16(Bb + k0s + (long)(e >> 5) * ldb + (e & 31),                    \
                    &ldsB[(BUF) * BN * 32 + i * 2048 + wid * 512]);                \
        }                                                                          \
    }

    STAGE(0, 0);
    if (nt > 1) STAGE(1, 1);

    for (int t = 0; t < nt; ++t) {
        const int buf = t % 3;
        if (t + 1 < nt) {
            if constexpr (LOADS == 2)      asm volatile("s_waitcnt vmcnt(2)" ::: "memory");
            else if constexpr (LOADS == 3) asm volatile("s_waitcnt vmcnt(3)" ::: "memory");
            else                           asm volatile("s_waitcnt vmcnt(4)" ::: "memory");
        } else {
            asm volatile("s_waitcnt vmcnt(0)" ::: "memory");
        }
        __syncthreads();
        if (t + 2 < nt) STAGE(t + 2, (t + 2) % 3);

        s16x8 af[FM], bfr[FN];
        #pragma unroll
        for (int m = 0; m < FM; ++m)
            af[m] = *(const s16x8*)&ldsA[buf * BM * 32 + (wr * WM + m * 16 + fr) * 32 + fk];
        #pragma unroll
        for (int n = 0; n < FN; ++n)
            bfr[n] = *(const s16x8*)&ldsB[buf * BN * 32 + (wc * WN + n * 16 + fr) * 32 + fk];
        #pragma unroll
        for (int m = 0; m < FM; ++m)
            #pragma unroll
            for (int n = 0; n < FN; ++n)
                acc[m][n] = __builtin_amdgcn_mfma_f32_16x16x32_bf16(af[m], bfr[n], acc[m][n], 0, 0, 0);
    }
#undef STAGE

    const int cj = lane & 15;
    const int r0 = (lane >> 4) * 4;

    if constexpr (EPI == 0) {
        const int seg = col0 >> 10;
        const int bb = row0 >> 10;
        __syncthreads();
        if (seg < 2) {
            #pragma unroll
            for (int m = 0; m < FM; ++m)
                #pragma unroll
                for (int n = 0; n < FN; ++n)
                    #pragma unroll
                    for (int r = 0; r < 4; ++r) {
                        const int prow = wr * WM + m * 16 + r0 + r;
                        const int pcol = wc * WN + n * 16 + cj;
                        float v = acc[m][n][r] + bias[col0 + pcol];
                        if (seg == 0) v *= 0.125f;
                        shm[prow * STR + pcol] = f2b(v);
                    }
            __syncthreads();
            #pragma unroll
            for (int j = 0; j < 8; ++j) {
                const int idx = j * 2048 + tid * 8;
                const int row = idx >> 7, c = idx & 127;
                s16x8 val = *(const s16x8*)&shm[row * STR + c];
                const int t = (row0 + row) & 1023;
                const int hh = ((col0 & 1023) >> 6) + (c >> 6);
                const int dd = c & 63;
                const long bh = bb * 16 + hh;
                *(s16x8*)(outB + (seg == 1 ? 4194304 : 0) + (bh << 16) + (t << 6) + dd) = val;
            }
        } else {
            #pragma unroll
            for (int m = 0; m < FM; ++m)
                #pragma unroll
                for (int n = 0; n < FN; ++n)
                    #pragma unroll
                    for (int r = 0; r < 4; ++r) {
                        const int prow = wr * WM + m * 16 + r0 + r;
                        const int pcol = wc * WN + n * 16 + cj;
                        shm[pcol * 144 + prow] = f2b(acc[m][n][r] + bias[col0 + pcol]);
                    }
            __syncthreads();
            #pragma unroll
            for (int j = 0; j < 8; ++j) {
                const int idx = j * 2048 + tid * 8;
                const int ddl = idx >> 7, tl = idx & 127;
                s16x8 val = *(const s16x8*)&shm[ddl * 144 + tl];
                const int hh = ((col0 & 1023) >> 6) + (ddl >> 6);
                const int dd = ddl & 63;
                const int t = (row0 & 1023) + tl;
                const long bh = bb * 16 + hh;
                *(s16x8*)(outB + 8388608 + (bh << 16) + (dd << 10) + t) = val;
            }
        }
    } else if constexpr (EPI == 4) {
        __syncthreads();
        #pragma unroll
        for (int m = 0; m < FM; ++m)
            #pragma unroll
            for (int n = 0; n < FN; ++n)
                #pragma unroll
                for (int r = 0; r < 4; ++r) {
                    const int prow = wr * WM + m * 16 + r0 + r;
                    const int pcol = wc * WN + n * 16 + cj;
                    float u = acc[m][n][r] + bias[col0 + pcol];
                    shm[prow * STR + pcol] = f2b(gelu_t(u));
                }
        __syncthreads();
        #pragma unroll
        for (int j = 0; j < 8; ++j) {
            const int idx = j * 2048 + tid * 8;
            const int row = idx >> 7, c = idx & 127;
            s16x8 val = *(const s16x8*)&shm[row * STR + c];
            *(s16x8*)(outB + (long)(row0 + row) * ldc + col0 + c) = val;
        }
    } else {
        // EPI 3: bias + residual -> fp32, coalesced via fp32 LDS repack
        float* shf = (float*)shm;
        __syncthreads();
        #pragma unroll
        for (int m = 0; m < FM; ++m)
            #pragma unroll
            for (int n = 0; n < FN; ++n)
                #pragma unroll
                for (int r = 0; r < 4; ++r) {
                    const int prow = wr * WM + m * 16 + r0 + r;
                    const int pcol = wc * WN + n * 16 + cj;
                    shf[prow * STRF + pcol] = acc[m][n][r];
                }
        __syncthreads();
        #pragma unroll
        for (int j = 0; j < (BM * BN / 1024); ++j) {
            const int idx = j * 1024 + tid * 4;
            const int row = idx >> 7, c = idx & 127;
            f32x4 v = *(const f32x4*)&shf[row * STRF + c];
            const long gbase = ((long)(row0 + row) << 10) + col0 + c;
            f32x4 bv = *(const f32x4*)(bias + col0 + c);
            f32x4 rv = *(const f32x4*)(resid + gbase);
            #pragma unroll
            for (int q = 0; q < 4; ++q) v[q] += bv[q] + rv[q];
            *(f32x4*)(outF + gbase) = v;
        }
    }
}

// ---------------- launch ----------------
extern "C" void kernel_launch(void* const* d_in, const int* in_sizes, int n_in,
                              void* d_out, int out_size, void* d_ws, size_t ws_size,
                              hipStream_t stream) {
    (void)in_sizes; (void)n_in; (void)out_size; (void)ws_size;
    const float* x     = (const float*)d_in[0];
    const float* mask  = (const float*)d_in[1];
    const float* ln1w  = (const float*)d_in[2];
    const float* ln1b  = (const float*)d_in[3];
    const float* wqkv  = (const float*)d_in[4];
    const float* bqkv  = (const float*)d_in[5];
    const float* wo    = (const float*)d_in[6];
    const float* bo    = (const float*)d_in[7];
    const float* ln2w  = (const float*)d_in[8];
    const float* ln2b  = (const float*)d_in[9];
    const float* wfc   = (const float*)d_in[10];
    const float* bfc   = (const float*)d_in[11];
    const float* wproj = (const float*)d_in[12];
    const float* bproj = (const float*)d_in[13];

    float* outx = (float*)d_out;                     // [4096,1024] fp32
    float* att  = (float*)d_out + 4194304;           // [64,1024,1024] fp32

    char* ws = (char*)d_ws;
    unsigned short* h_bf     = (unsigned short*)ws;  ws += (size_t)8  << 20;  // [4096,1024]
    unsigned short* wqkv_bf  = (unsigned short*)ws;  ws += (size_t)6  << 20;  // [3072,1024]
    unsigned short* wo_bf    = (unsigned short*)ws;  ws += (size_t)2  << 20;  // [1024,1024]
    unsigned short* wfc_bf   = (unsigned short*)ws;  ws += (size_t)8  << 20;  // [4096,1024]
    unsigned short* wproj_bf = (unsigned short*)ws;  ws += (size_t)8  << 20;  // [1024,4096]
    unsigned short* q_bf     = (unsigned short*)ws;  ws += (size_t)24 << 20;  // q,k,vT contiguous
    unsigned short* k_bf     = q_bf + 4194304;
    unsigned short* vT_bf    = q_bf + 8388608;
    unsigned short* y_bf     = (unsigned short*)ws;  ws += (size_t)8  << 20;  // [4096,1024]
    float*          x2       = (float*)ws;           ws += (size_t)16 << 20;  // [4096,1024] f32
    unsigned short* gelu_bf  = (unsigned short*)ws;  ws += (size_t)32 << 20;  // [4096,4096]

    // cast weights + LN1 in one launch
    castln_kernel<<<16384, 256, 0, stream>>>(
        x, ln1w, ln1b, h_bf,
        wqkv, 786432, wo, 262144, wfc, 1048576, wproj, 1048576,
        wqkv_bf, wo_bf, wfc_bf, wproj_bf);

    // QKV: [4096,1024] x [3072,1024]^T -> q(scaled)/k/vT scatter (repacked stores)
    gemm_bt<128, 128, 0><<<dim3(32, 24, 1), 256, 0, stream>>>(
        h_bf, wqkv_bf, 1024, 1024, 1024, 0, 0, 0,
        bqkv, nullptr, nullptr, q_bf);

    // fused attention: rowsums (pass A) + att fp32 + PV (pass B)
    attn_all<<<dim3(16, 64), 256, 0, stream>>>(
        q_bf, k_bf, vT_bf, mask, att, y_bf);

    // W_o: [4096,1024] x [1024,1024]^T + b_o + x -> x2
    gemm_bt<64, 128, 3><<<dim3(64, 8, 1), 256, 0, stream>>>(
        y_bf, wo_bf, 1024, 1024, 1024, 1024, 0, 0,
        bo, x, x2, nullptr);

    // LN2
    ln_kernel<<<4096, 256, 0, stream>>>(x2, ln2w, ln2b, h_bf);

    // FC + GELU: [4096,1024] x [4096,1024]^T -> gelu_bf
    gemm_bt<128, 128, 4><<<dim3(32, 32, 1), 256, 0, stream>>>(
        h_bf, wfc_bf, 1024, 1024, 1024, 4096, 0, 0,
        bfc, nullptr, nullptr, gelu_bf);

    // Proj: [4096,4096] x [1024,4096]^T + b_proj + x2 -> out
    gemm_bt<64, 128, 3><<<dim3(64, 8, 1), 256, 0, stream>>>(
        gelu_bf, wproj_bf, 4096, 4096, 4096, 1024, 0, 0,
        bproj, x2, outx, nullptr);
}